// Round 3
// baseline (422.901 us; speedup 1.0000x reference)
//
#include <hip/hip_runtime.h>

// Problem constants (from reference): B=16,N=100,E=9900,M=50,F=64,H=128,K=20,D=2,T=8,S=8
#define BB 16
#define NN 100
#define EE 9900
#define MM 50
#define FF 64
#define HH 128
#define KK 20
#define DD 2
#define ROWS (BB*EE)      // 158400 edge rows
#define HROWS (BB*MM)     // 800 hyper rows
#define BN_CNT (BB*NN)    // 1600

#define EPSF 1e-5f

__device__ __forceinline__ float lrelu(float x) { return (x >= 0.f) ? x : 0.01f * x; }

// ---------------- Threefry-2x32 (bit-exact vs JAX) ----------------
__device__ __forceinline__ void tf2x32(unsigned k0, unsigned k1,
                                       unsigned x0, unsigned x1,
                                       unsigned& o0, unsigned& o1) {
  unsigned ks2 = k0 ^ k1 ^ 0x1BD11BDAu;
  x0 += k0; x1 += k1;
#define TFR(r) { x0 += x1; x1 = (x1 << r) | (x1 >> (32 - r)); x1 ^= x0; }
  TFR(13) TFR(15) TFR(26) TFR(6)   x0 += k1;  x1 += ks2 + 1u;
  TFR(17) TFR(29) TFR(16) TFR(24)  x0 += ks2; x1 += k0 + 2u;
  TFR(13) TFR(15) TFR(26) TFR(6)   x0 += k0;  x1 += k1 + 3u;
  TFR(17) TFR(29) TFR(16) TFR(24)  x0 += k1;  x1 += ks2 + 4u;
  TFR(13) TFR(15) TFR(26) TFR(6)   x0 += ks2; x1 += k0 + 5u;
#undef TFR
  o0 = x0; o1 = x1;
}

// bits -> N(0,1) matching jax.random.normal f32 path (uniform in [lo,1), sqrt2*erfinv)
__device__ __forceinline__ float bits_to_normal(unsigned bits) {
  float f = __uint_as_float((bits >> 9) | 0x3f800000u) - 1.0f;  // [0,1)
  const float lo = -0.99999994f;                                 // nextafter(-1,0)
  float x = fmaxf(lo, fmaf(f, 2.0f, lo));                        // (hi-lo)==2.0f exactly
  float w = -log1pf(-x * x);
  float p;
  if (w < 5.0f) {
    w = w - 2.5f;
    p = 2.81022636e-08f;
    p = fmaf(p, w, 3.43273939e-07f);
    p = fmaf(p, w, -3.5233877e-06f);
    p = fmaf(p, w, -4.39150654e-06f);
    p = fmaf(p, w, 0.00021858087f);
    p = fmaf(p, w, -0.00125372503f);
    p = fmaf(p, w, -0.00417768164f);
    p = fmaf(p, w, 0.246640727f);
    p = fmaf(p, w, 1.50140941f);
  } else {
    w = sqrtf(w) - 3.0f;
    p = -0.000200214257f;
    p = fmaf(p, w, 0.000100950558f);
    p = fmaf(p, w, 0.00134934322f);
    p = fmaf(p, w, -0.00367342844f);
    p = fmaf(p, w, 0.00573950773f);
    p = fmaf(p, w, -0.0076224613f);
    p = fmaf(p, w, 0.00943887047f);
    p = fmaf(p, w, 1.00167406f);
    p = fmaf(p, w, 2.83297682f);
  }
  return 1.41421356237f * (p * x);
}

// ---------------- scales: mean over last dim (4) ----------------
__global__ void k_scales(const float* __restrict__ rtg, const float* __restrict__ rth,
                         float* __restrict__ sg, float* __restrict__ sh) {
  int i = blockIdx.x * blockDim.x + threadIdx.x;
  if (i < ROWS) {
    float4 r = ((const float4*)rtg)[i];
    sg[i] = (r.x + r.y + r.z + r.w) * 0.25f;
  }
  int j = i - ROWS;
  if (j >= 0 && j < HROWS) {
    float4 r = ((const float4*)rth)[j];
    sh[j] = (r.x + r.y + r.z + r.w) * 0.25f;
  }
}

// ---------------- edge MLP layer (fused gather / bn+lrelu staging + GEMM + stats) -------
// MODE 0: X = [recv|send] gathered from v_combined;  Y <- X@W + b, stats_out += col sums
// MODE 1: X = lrelu(bn(Y; stats_in,g,beta));         Y <- X@W + b (in-place), stats_out
template <int MODE>
__global__ __launch_bounds__(256) void k_edge_gemm(
    const float* __restrict__ v, float* __restrict__ Y,
    const float* __restrict__ W, const float* __restrict__ bias,
    const float* __restrict__ gmm, const float* __restrict__ beta,
    const float* __restrict__ stats_in, float* __restrict__ stats_out) {
  __shared__ __align__(16) float Wl[64][128];
  __shared__ __align__(16) float Xt[64][68];
  __shared__ float bsum[128], bssq[128];
  __shared__ float aCol[128], bCol[128];
  const int tid = threadIdx.x;
  const int r0 = blockIdx.x * 64;

  if (tid < 128) {
    bsum[tid] = 0.f; bssq[tid] = 0.f;
    if (MODE == 1) {
      float s = stats_in[tid], ss = stats_in[128 + tid];
      float mu = s * (1.f / ROWS);
      float var = fmaxf(ss * (1.f / ROWS) - mu * mu, 0.f);
      float rs = 1.f / sqrtf(var + EPSF);
      float a = rs * gmm[tid];
      aCol[tid] = a; bCol[tid] = beta[tid] - mu * a;
    }
  }

  const int rsi = tid >> 2;            // staging row 0..63
  const int kbase = (tid & 3) * 16;    // staging k offset
  const int g = r0 + rsi;
  int vrow0 = 0, vrow1 = 0;
  if (MODE == 0) {
    int b = g / EE; int e = g - b * EE;
    int i = e / 99; int jj = e - i * 99; int j = jj + ((jj >= i) ? 1 : 0);
    vrow0 = (b * NN + i) * FF;  // recv
    vrow1 = (b * NN + j) * FF;  // send
  }
  const int tx = tid & 31, ty = tid >> 5;
  float acc[8][4];
#pragma unroll
  for (int q = 0; q < 8; ++q)
#pragma unroll
    for (int u = 0; u < 4; ++u) acc[q][u] = 0.f;
  __syncthreads();

  for (int kk = 0; kk < 128; kk += 64) {
    { // stage W half (64x128)
      const float4* Wg = (const float4*)(W + kk * 128);
      float4* Wl4 = (float4*)&Wl[0][0];
#pragma unroll
      for (int q = 0; q < 8; ++q) Wl4[q * 256 + tid] = Wg[q * 256 + tid];
    }
    if (MODE == 0) {
      const float4* src = (const float4*)(v + ((kk == 0) ? vrow0 : vrow1) + kbase);
#pragma unroll
      for (int q = 0; q < 4; ++q) {
        float4 t4 = src[q];
        Xt[kbase + q * 4 + 0][rsi] = t4.x;
        Xt[kbase + q * 4 + 1][rsi] = t4.y;
        Xt[kbase + q * 4 + 2][rsi] = t4.z;
        Xt[kbase + q * 4 + 3][rsi] = t4.w;
      }
    } else {
      const float4* src = (const float4*)(Y + (size_t)g * 128 + kk + kbase);
#pragma unroll
      for (int q = 0; q < 4; ++q) {
        float4 t4 = src[q];
        float tv[4] = {t4.x, t4.y, t4.z, t4.w};
#pragma unroll
        for (int u = 0; u < 4; ++u) {
          int col = kk + kbase + q * 4 + u;
          float x = tv[u] * aCol[col] + bCol[col];
          Xt[kbase + q * 4 + u][rsi] = lrelu(x);
        }
      }
    }
    __syncthreads();
#pragma unroll 4
    for (int k = 0; k < 64; ++k) {
      float4 w4 = *(const float4*)&Wl[k][tx * 4];
      float4 xa = *(const float4*)&Xt[k][ty * 8];
      float4 xb = *(const float4*)&Xt[k][ty * 8 + 4];
      float xr[8] = {xa.x, xa.y, xa.z, xa.w, xb.x, xb.y, xb.z, xb.w};
#pragma unroll
      for (int q = 0; q < 8; ++q) {
        acc[q][0] = fmaf(xr[q], w4.x, acc[q][0]);
        acc[q][1] = fmaf(xr[q], w4.y, acc[q][1]);
        acc[q][2] = fmaf(xr[q], w4.z, acc[q][2]);
        acc[q][3] = fmaf(xr[q], w4.w, acc[q][3]);
      }
    }
    __syncthreads();
  }
  // epilogue: +bias, store, block stats
  float b4[4];
#pragma unroll
  for (int u = 0; u < 4; ++u) b4[u] = bias[tx * 4 + u];
  float ps[4] = {0, 0, 0, 0}, pss[4] = {0, 0, 0, 0};
#pragma unroll
  for (int q = 0; q < 8; ++q) {
    int gr = r0 + ty * 8 + q;
    float4 yv;
    float yy0 = acc[q][0] + b4[0];
    float yy1 = acc[q][1] + b4[1];
    float yy2 = acc[q][2] + b4[2];
    float yy3 = acc[q][3] + b4[3];
    yv.x = yy0; yv.y = yy1; yv.z = yy2; yv.w = yy3;
    ps[0] += yy0; pss[0] += yy0 * yy0;
    ps[1] += yy1; pss[1] += yy1 * yy1;
    ps[2] += yy2; pss[2] += yy2 * yy2;
    ps[3] += yy3; pss[3] += yy3 * yy3;
    *(float4*)&Y[(size_t)gr * 128 + tx * 4] = yv;
  }
#pragma unroll
  for (int u = 0; u < 4; ++u) {
    atomicAdd(&bsum[tx * 4 + u], ps[u]);
    atomicAdd(&bssq[tx * 4 + u], pss[u]);
  }
  __syncthreads();
  if (tid < 128) {
    atomicAdd(&stats_out[tid], bsum[tid]);
    atomicAdd(&stats_out[128 + tid], bssq[tid]);
  }
}

// ---------------- receiver gather-reduce: hidden_g ----------------
__global__ __launch_bounds__(128) void k_recv(
    const float* __restrict__ Y, const float* __restrict__ stats2,
    const float* __restrict__ g2, const float* __restrict__ be2,
    const float* __restrict__ scaleg, const float* __restrict__ v,
    float* __restrict__ hg) {
  int bn = blockIdx.x; int b = bn / NN, n = bn - b * NN;
  int h = threadIdx.x;
  float s = stats2[h], ss = stats2[128 + h];
  float mu = s * (1.f / ROWS);
  float var = fmaxf(ss * (1.f / ROWS) - mu * mu, 0.f);
  float rs = 1.f / sqrtf(var + EPSF);
  float a = rs * g2[h]; float bc = be2[h] - mu * a;
  float sv = (h >= 64) ? v[(b * NN + n) * FF + (h - 64)] : 0.f;
  float acc = 0.f;
  for (int i = 0; i < NN; ++i) {
    if (i == n) continue;
    int e = i * 99 + ((n < i) ? n : n - 1);
    int row = b * EE + e;
    float y = Y[(size_t)row * 128 + h];
    float msgv = lrelu(y * a + bc);
    float pre = (h < 64) ? v[(b * NN + i) * FF + h] : sv;
    float ag = lrelu(fmaf(msgv, scaleg[row], pre));
    acc += ag;
  }
  hg[bn * 128 + h] = acc * 0.5f;  // / D
}

// ---------------- hyper path ----------------
__global__ __launch_bounds__(128) void k_h1(const float* __restrict__ I_HG,
                                            const float* __restrict__ v,
                                            const float* __restrict__ W1h,
                                            const float* __restrict__ b1h,
                                            float* __restrict__ y1h) {
  int bm = blockIdx.x; int b = bm / MM, m = bm - b * MM;
  __shared__ float prerow[FF];
  int t = threadIdx.x;
  if (t < FF) {
    float s = 0.f;
    for (int n = 0; n < NN; ++n)
      s = fmaf(I_HG[(b * NN + n) * MM + m], v[(b * NN + n) * FF + t], s);
    prerow[t] = s;
  }
  __syncthreads();
  float y = b1h[t];
  for (int f = 0; f < FF; ++f) y = fmaf(prerow[f], W1h[f * 128 + t], y);
  y1h[bm * 128 + t] = y;
}

__global__ __launch_bounds__(64) void k_colstats(const float* __restrict__ X, int R,
                                                 float* __restrict__ stats) {
  int c = blockIdx.x;  // 128 blocks
  int t = threadIdx.x; // 64
  float s = 0.f, ss = 0.f;
  for (int r = t; r < R; r += 64) {
    float x = X[(size_t)r * 128 + c];
    s += x; ss += x * x;
  }
  for (int off = 32; off; off >>= 1) {
    s += __shfl_down(s, off, 64);
    ss += __shfl_down(ss, off, 64);
  }
  if (t == 0) { stats[c] = s; stats[128 + c] = ss; }
}

__global__ __launch_bounds__(128) void k_h2(const float* __restrict__ y1h,
                                            const float* __restrict__ statsh1,
                                            const float* __restrict__ g1h,
                                            const float* __restrict__ be1h,
                                            const float* __restrict__ W2h,
                                            const float* __restrict__ b2h,
                                            float* __restrict__ y2h) {
  int bm = blockIdx.x; int t = threadIdx.x;
  __shared__ float trow[128];
  float s = statsh1[t], ss = statsh1[128 + t];
  float mu = s * (1.f / HROWS);
  float var = fmaxf(ss * (1.f / HROWS) - mu * mu, 0.f);
  float rs = 1.f / sqrtf(var + EPSF);
  float a = rs * g1h[t]; float bc = be1h[t] - mu * a;
  trow[t] = lrelu(y1h[bm * 128 + t] * a + bc);
  __syncthreads();
  float y = b2h[t];
  for (int f = 0; f < 128; ++f) y = fmaf(trow[f], W2h[f * 128 + t], y);
  y2h[bm * 128 + t] = y;
}

__global__ __launch_bounds__(128) void k_h3(const float* __restrict__ y2h,
                                            const float* __restrict__ statsh2,
                                            const float* __restrict__ g2h,
                                            const float* __restrict__ be2h,
                                            const float* __restrict__ scaleh,
                                            const float* __restrict__ I_HG,
                                            float* __restrict__ hh) {
  int bn = blockIdx.x; int b = bn / NN, n = bn - b * NN;
  int h = threadIdx.x;
  float s = statsh2[h], ss = statsh2[128 + h];
  float mu = s * (1.f / HROWS);
  float var = fmaxf(ss * (1.f / HROWS) - mu * mu, 0.f);
  float rs = 1.f / sqrtf(var + EPSF);
  float a = rs * g2h[h]; float bc = be2h[h] - mu * a;
  float acc = 0.f;
  for (int m = 0; m < MM; ++m) {
    float x = lrelu(y2h[(b * MM + m) * 128 + h] * a + bc);
    acc = fmaf(x * scaleh[b * MM + m], I_HG[(b * NN + n) * MM + m], acc);
  }
  hh[bn * 128 + h] = acc * 0.5f;  // / D
}

// ---------------- v layer + heads ----------------
__global__ __launch_bounds__(128) void k_ve(
    const float* __restrict__ hg, const float* __restrict__ hh,
    const float* __restrict__ Wo1, const float* __restrict__ bo1,
    const float* __restrict__ Wa, const float* __restrict__ ba,
    const float* __restrict__ Wm, const float* __restrict__ bm,
    float* __restrict__ valpha, float* __restrict__ vmu, float* __restrict__ vcore) {
  __shared__ __align__(16) float cat[8][256];
  __shared__ float vres[8][128];
  __shared__ float lgs[KK], mrow[KK * DD], alsh[KK];
  int r0 = blockIdx.x * 8;
  int t = threadIdx.x;
  for (int q = t; q < 2048; q += 128) {
    int rr = q >> 8, k = q & 255;
    cat[rr][k] = (k < 128) ? hg[(r0 + rr) * 128 + k] : hh[(r0 + rr) * 128 + (k - 128)];
  }
  __syncthreads();
  float acc[8] = {0, 0, 0, 0, 0, 0, 0, 0};
  for (int k = 0; k < 256; ++k) {
    float wv = Wo1[k * 128 + t];
#pragma unroll
    for (int q = 0; q < 8; ++q) acc[q] = fmaf(cat[q][k], wv, acc[q]);
  }
  float bb = bo1[t];
#pragma unroll
  for (int q = 0; q < 8; ++q) vres[q][t] = lrelu(acc[q] + bb);
  __syncthreads();
  for (int q = 0; q < 8; ++q) {
    int row = r0 + q;
    if (t < KK) {
      float s = ba[t];
      for (int f = 0; f < 128; ++f) s = fmaf(vres[q][f], Wa[f * KK + t], s);
      lgs[t] = s;
    } else if (t >= 64 && t < 64 + KK * DD) {
      int c = t - 64;
      float s = bm[c];
      for (int f = 0; f < 128; ++f) s = fmaf(vres[q][f], Wm[f * (KK * DD) + c], s);
      mrow[c] = s;
      vmu[row * (KK * DD) + c] = s;
    }
    __syncthreads();
    if (t < KK) {
      float mx = lgs[0];
      for (int k2 = 1; k2 < KK; ++k2) mx = fmaxf(mx, lgs[k2]);
      float se = 0.f;
      for (int k2 = 0; k2 < KK; ++k2) se += expf(lgs[k2] - mx);
      float al = expf(lgs[t] - mx) / se;
      alsh[t] = al;
      valpha[row * KK + t] = al;
    }
    __syncthreads();
    if (t < DD) {
      float s = 0.f;
      for (int k2 = 0; k2 < KK; ++k2) s = fmaf(alsh[k2], mrow[k2 * DD + t], s);
      vcore[row * DD + t] = s;
    }
    __syncthreads();
  }
}

// ---------------- decoder outputs (exact JAX threefry noise) ----------------
// JAX jax_threefry_partitionable=True (modern default), 32-bit path:
//   bits1, bits2 = threefry2x32(key, (counts_hi=0, counts_lo=flat_idx))
//   bits = bits1 ^ bits2          <-- XOR of both output lanes
// fold_in(key, s) = threefry_2x32(key, threefry_seed(s)) = tf(key, [0, s]).
__global__ __launch_bounds__(64) void k_out(const float* __restrict__ data,
                                            const float* __restrict__ valpha,
                                            const float* __restrict__ vmu,
                                            const float* __restrict__ vcore,
                                            float* __restrict__ out) {
  int bn = blockIdx.x; int t = threadIdx.x;
  __shared__ float nz[8][2];
  __shared__ float insarr[8][2];
  __shared__ float alsh[KK];
  if (t < 16) {
    int s = t >> 1, d = t & 1;
    unsigned fk0, fk1;
    tf2x32(0u, 1234u, 0u, (unsigned)s, fk0, fk1);        // fold_in(key(1234), s)
    unsigned flat = (unsigned)(bn * 2 + d);               // flat index into (B,N,D)=3200
    unsigned o0, o1;
    tf2x32(fk0, fk1, 0u, flat, o0, o1);                   // counter-mode: x=(hi=0, lo=flat)
    nz[s][d] = bits_to_normal(o0 ^ o1);                   // 32-bit path: XOR both lanes
  }
  if (t < KK) alsh[t] = valpha[bn * KK + t];
  __syncthreads();
  if (t < 2) {
    int d = t;
    float ins0 = data[bn * 16 + d];  // data[b,n,0,d]
    float core = vcore[bn * 2 + d];
    float p = ins0;
    for (int s = 0; s < 8; ++s) {
      insarr[s][d] = p;                       // ins at step s
      p = (p + core) + nz[s][d];              // preds[s]
      out[(bn * 8 + s) * 2 + d] = p;
    }
  }
  __syncthreads();
  // alphas (B,N,S,K)
  for (int q = t; q < 160; q += 64) {
    int k = q % KK;
    out[25600 + bn * 160 + q] = alsh[k];
  }
  // mus (B,N,S,K,D)
  for (int q = t; q < 320; q += 64) {
    int s = q / 40, kd = q - s * 40, d = kd & 1;
    out[281600 + bn * 320 + q] = vmu[bn * 40 + kd] + insarr[s][d];
  }
  // sigmas = 1
  for (int q = t; q < 320; q += 64) out[793600 + bn * 320 + q] = 1.0f;
}

// ---------------- workspace layout (floats) ----------------
#define OFF_Y       ((size_t)0)
#define OFF_STATS1  ((size_t)20275200)        // ROWS*128
#define OFF_STATS2  (OFF_STATS1 + 256)
#define OFF_STATSH1 (OFF_STATS2 + 256)
#define OFF_STATSH2 (OFF_STATSH1 + 256)
#define OFF_SCALEG  (OFF_STATSH2 + 256)
#define OFF_SCALEH  (OFF_SCALEG + ROWS)
#define OFF_HG      (OFF_SCALEH + HROWS)
#define OFF_HH      (OFF_HG + (size_t)BN_CNT * 128)
#define OFF_Y1H     (OFF_HH + (size_t)BN_CNT * 128)
#define OFF_Y2H     (OFF_Y1H + (size_t)HROWS * 128)
#define OFF_VA      (OFF_Y2H + (size_t)HROWS * 128)
#define OFF_VMU     (OFF_VA + (size_t)BN_CNT * KK)
#define OFF_VCORE   (OFF_VMU + (size_t)BN_CNT * KK * DD)

extern "C" void kernel_launch(void* const* d_in, const int* in_sizes, int n_in,
                              void* d_out, int out_size, void* d_ws, size_t ws_size,
                              hipStream_t stream) {
  const float* data  = (const float*)d_in[0];
  // d_in[1] rel_rec_g, d_in[2] rel_send_g: one-hot with known analytic structure
  const float* rtg   = (const float*)d_in[3];
  const float* rth   = (const float*)d_in[4];
  const float* I_HG  = (const float*)d_in[5];
  const float* v     = (const float*)d_in[6];
  const float* W1g   = (const float*)d_in[7];
  const float* b1g   = (const float*)d_in[8];
  const float* g1g   = (const float*)d_in[9];
  const float* be1g  = (const float*)d_in[10];
  const float* W2g   = (const float*)d_in[11];
  const float* b2g   = (const float*)d_in[12];
  const float* g2g   = (const float*)d_in[13];
  const float* be2g  = (const float*)d_in[14];
  const float* W1h   = (const float*)d_in[15];
  const float* b1h   = (const float*)d_in[16];
  const float* g1h   = (const float*)d_in[17];
  const float* be1h  = (const float*)d_in[18];
  const float* W2h   = (const float*)d_in[19];
  const float* b2h   = (const float*)d_in[20];
  const float* g2h   = (const float*)d_in[21];
  const float* be2h  = (const float*)d_in[22];
  const float* Wo1   = (const float*)d_in[23];
  const float* bo1   = (const float*)d_in[24];
  const float* Wa    = (const float*)d_in[25];
  const float* ba    = (const float*)d_in[26];
  const float* Wm    = (const float*)d_in[27];
  const float* bm    = (const float*)d_in[28];
  float* ws  = (float*)d_ws;
  float* out = (float*)d_out;

  float* Y       = ws + OFF_Y;
  float* stats1  = ws + OFF_STATS1;
  float* stats2  = ws + OFF_STATS2;
  float* statsh1 = ws + OFF_STATSH1;
  float* statsh2 = ws + OFF_STATSH2;
  float* scaleg  = ws + OFF_SCALEG;
  float* scaleh  = ws + OFF_SCALEH;
  float* hg      = ws + OFF_HG;
  float* hh      = ws + OFF_HH;
  float* y1h     = ws + OFF_Y1H;
  float* y2h     = ws + OFF_Y2H;
  float* va      = ws + OFF_VA;
  float* vmu     = ws + OFF_VMU;
  float* vcore   = ws + OFF_VCORE;

  hipMemsetAsync(stats1, 0, 1024 * sizeof(float), stream);  // 4 stats blocks contiguous
  k_scales<<<(ROWS + HROWS + 255) / 256, 256, 0, stream>>>(rtg, rth, scaleg, scaleh);
  k_edge_gemm<0><<<ROWS / 64, 256, 0, stream>>>(v, Y, W1g, b1g, nullptr, nullptr, nullptr, stats1);
  k_edge_gemm<1><<<ROWS / 64, 256, 0, stream>>>(v, Y, W2g, b2g, g1g, be1g, stats1, stats2);
  k_recv<<<BN_CNT, 128, 0, stream>>>(Y, stats2, g2g, be2g, scaleg, v, hg);
  k_h1<<<HROWS, 128, 0, stream>>>(I_HG, v, W1h, b1h, y1h);
  k_colstats<<<128, 64, 0, stream>>>(y1h, HROWS, statsh1);
  k_h2<<<HROWS, 128, 0, stream>>>(y1h, statsh1, g1h, be1h, W2h, b2h, y2h);
  k_colstats<<<128, 64, 0, stream>>>(y2h, HROWS, statsh2);
  k_h3<<<BN_CNT, 128, 0, stream>>>(y2h, statsh2, g2h, be2h, scaleh, I_HG, hh);
  k_ve<<<BN_CNT / 8, 128, 0, stream>>>(hg, hh, Wo1, bo1, Wa, ba, Wm, bm, va, vmu, vcore);
  k_out<<<BN_CNT, 64, 0, stream>>>(data, va, vmu, vcore, out);
}